// Round 2
// baseline (550.867 us; speedup 1.0000x reference)
//
#include <hip/hip_runtime.h>
#include <stdint.h>

// GiddLinearNoise.sample_zt on MI355X (gfx950).
//
// z_t[b,s] = argmax_v ( ((1-t_b)*onehot(id)[v] + t_b*pi[v]) / (1e-10 - log(u[b,s,v] + 1e-10)) )
// u = jax.random.uniform(key(1), (4,1024,50257), f32).
//
// JAX >= 0.4.30 defaults jax_threefry_partitionable=True, so random bits come from the
// PARTITIONABLE stream: per-element 64-bit counter = flat index i, threefry2x32 with
// key (0,1) on (x0,x1) = (i>>32, i&0xffffffff) = (0, i) here (size < 2^32), and the
// 32-bit output is the XOR fold: bits[i] = y0 ^ y1.
//
// u = (bits>>9) * 2^-23 EXACTLY (bitcast((bits>>9)|0x3f800000) - 1 is exact). All generic
// tokens (v != MASK, v != id) share ONE probability float p => q = p/g(u) is strictly
// monotone decreasing in g, i.e. monotone increasing in the 23-bit mantissa k (per-k-step
// >= ~5 ulp of q since max u*(-ln u) = 1/e), so the generic argmax is (max k, min v on tie),
// independent of log() implementation. Only 3 candidates per row (generic winner, MASK,
// input_id) go through the exact float pipeline, on thread 0.

namespace {

constexpr int VOCAB = 50257;
constexpr int MASK = 50256;   // last index
constexpr int TPB = 256;
constexpr int NROWS = 4096;   // B*S
constexpr int NITER = (VOCAB + TPB - 1) / TPB;  // 197

__device__ __forceinline__ void tf_round(uint32_t& x0, uint32_t& x1, const int r) {
  x0 += x1;
  x1 = (x1 << r) | (x1 >> (32 - r));   // -> v_alignbit_b32
  x1 ^= x0;
}

// Threefry-2x32, 20 rounds, key (0,1): ks0=0, ks1=1, ks2=0^1^0x1BD11BDA=0x1BD11BDB.
// Counter (0, i). Returns the partitionable 32-bit fold y0 ^ y1.
__device__ __forceinline__ uint32_t tf_bits01(uint32_t i) {
  const uint32_t ks2 = 0x1BD11BDBu;
  uint32_t x0 = 0u;            // c0(=0) + ks0(=0)
  uint32_t x1 = i + 1u;        // c1 + ks1(=1)
  tf_round(x0, x1, 13); tf_round(x0, x1, 15); tf_round(x0, x1, 26); tf_round(x0, x1, 6);
  x0 += 1u;        x1 += ks2 + 1u;
  tf_round(x0, x1, 17); tf_round(x0, x1, 29); tf_round(x0, x1, 16); tf_round(x0, x1, 24);
  x0 += ks2;       x1 += 2u;                    // ks0 + 2
  tf_round(x0, x1, 13); tf_round(x0, x1, 15); tf_round(x0, x1, 26); tf_round(x0, x1, 6);
  /* x0 += ks0 */  x1 += 1u + 3u;               // ks1 + 3
  tf_round(x0, x1, 17); tf_round(x0, x1, 29); tf_round(x0, x1, 16); tf_round(x0, x1, 24);
  x0 += 1u;        x1 += ks2 + 4u;
  tf_round(x0, x1, 13); tf_round(x0, x1, 15); tf_round(x0, x1, 26); tf_round(x0, x1, 6);
  x0 += ks2;       x1 += 5u;                    // ks0 + 5
  return x0 ^ x1;
}

// Exact replica of the reference float32 pipeline for one candidate.
__device__ __forceinline__ float qval(float p, uint32_t k) {
  const float u = (float)k * 0x1p-23f;          // == jax uniform value, exact
  const float g = 1e-10f - logf(u + 1e-10f);    // gumbel_norm (g > 0 always)
  return p / g;                                  // IEEE f32 divide
}

__global__ __launch_bounds__(TPB) void gidd_sample_zt(
    const int* __restrict__ ids, const float* __restrict__ t,
    const float* __restrict__ pi, int* __restrict__ out) {
  const int row = blockIdx.x;       // b*1024 + s
  const int b = row >> 10;
  const int tid = threadIdx.x;

  const int id = ids[row];
  const uint32_t base = (uint32_t)row * (uint32_t)VOCAB;

  // Generic-token scan: argmax of the raw 23-bit mantissa k (tie -> lowest v).
  uint32_t km = 0u;
  int vm = 0;

  uint32_t c = base + (uint32_t)tid;
  int v = tid;
#pragma unroll 1
  for (int it = 0; it < NITER; ++it) {
    const uint32_t k = tf_bits01(c) >> 9;
    const bool valid = (v < MASK) & (v != id);   // in-vocab, not mask, not input id
    if (valid && (k > km)) { km = k; vm = v; }   // strict > keeps lowest v per thread
    c += TPB;
    v += TPB;
  }

  // Wave reduction (64 lanes): (max k, min v on tie).
#pragma unroll
  for (int off = 32; off > 0; off >>= 1) {
    const uint32_t ok = __shfl_down(km, off);
    const int      ov = __shfl_down(vm, off);
    if (ok > km || (ok == km && ov < vm)) { km = ok; vm = ov; }
  }

  __shared__ uint32_t skm[4];
  __shared__ int svm[4];
  const int lane = tid & 63;
  const int wid = tid >> 6;
  if (lane == 0) { skm[wid] = km; svm[wid] = vm; }
  __syncthreads();

  if (tid == 0) {
    km = skm[0]; vm = svm[0];
    for (int w = 1; w < 4; ++w)
      if (skm[w] > km || (skm[w] == km && svm[w] < vm)) { km = skm[w]; vm = svm[w]; }

    const float tb = t[b];
    const float pic = pi[0];        // generic pi value (identical bits for all non-mask v)
    const float pim = pi[MASK];
    const float a = 1.0f - tb;      // alpha_t
    const float pc = tb * pic;      // generic prob
    const float pm = tb * pim;      // mask prob (without onehot)

    const uint32_t kmsk = tf_bits01(base + (uint32_t)MASK) >> 9;
    const uint32_t kid  = tf_bits01(base + (uint32_t)id) >> 9;

    float bq = qval(pc, km);
    int bv = vm;
    // MASK candidate (index 50256 > any generic index, so ties never replace).
    const float pmask = (id == MASK) ? (pm + a) : pm;
    const float qm = qval(pmask, kmsk);
    if (qm > bq) { bq = qm; bv = MASK; }
    // input-id candidate (first-index-of-max: replace on >, or == with smaller index).
    if (id != MASK) {
      const float qi = qval(pc + a, kid);
      if (qi > bq || (qi == bq && id < bv)) { bq = qi; bv = id; }
    }
    out[row] = bv;
  }
}

}  // namespace

extern "C" void kernel_launch(void* const* d_in, const int* in_sizes, int n_in,
                              void* d_out, int out_size, void* d_ws, size_t ws_size,
                              hipStream_t stream) {
  const int* ids  = (const int*)d_in[0];
  const float* t  = (const float*)d_in[1];
  const float* pi = (const float*)d_in[2];
  int* out = (int*)d_out;
  gidd_sample_zt<<<NROWS, TPB, 0, stream>>>(ids, t, pi, out);
}

// Round 3
// 426.657 us; speedup vs baseline: 1.2911x; 1.2911x over previous
//
#include <hip/hip_runtime.h>
#include <stdint.h>

// GiddLinearNoise.sample_zt on MI355X (gfx950).
//
// z_t[b,s] = argmax_v ( ((1-t_b)*onehot(id)[v] + t_b*pi[v]) / (1e-10 - log(u[b,s,v] + 1e-10)) )
// u = jax.random.uniform(key(1), (4,1024,50257), f32), partitionable threefry stream:
// bits[i] = fold(threefry2x32(key=(0,1), counter=(0,i))) = y0 ^ y1;  u = (bits>>9) * 2^-23.
//
// All generic tokens share ONE probability float => q is strictly monotone in the 23-bit
// mantissa k (>= ~5 ulp per k step since max u*(-ln u) = 1/e), so the generic argmax is
// (max k, min v on tie), log-free. The id/MASK positions are INCLUDED in the scan: if one
// spuriously wins, its exact candidate (strictly larger p, same u) dominates both the
// spurious q and every true generic q, so the 3-candidate exact epilogue stays correct.
//
// Inner loop per element: threefry (~66 VALU: alignbit rotates, add3-folded injections)
// + 3 VALU select (lshr, and_or, max/max3). Packed key = (k<<8)|(255-it): order =
// (k desc, it asc); min-tid tie via ballot+ffs => exact (max k, min v) semantics.

namespace {

constexpr int VOCAB = 50257;
constexpr int MASK  = 50256;   // last index
constexpr int TPB   = 256;
constexpr int NROWS = 4096;    // B*S

__device__ __forceinline__ uint32_t rotl(uint32_t x, int r) {
  return __builtin_rotateleft32(x, r);   // -> v_alignbit_b32
}

__device__ __forceinline__ uint32_t umax2(uint32_t a, uint32_t b) {
  return a > b ? a : b;                  // -> v_max_u32 / v_max3_u32 when nested
}

// Threefry-2x32-20, key (0,1), counter (0, c); caller passes x1_init = c + 1 (ks1 folded).
// Returns the partitionable fold y0 ^ y1. Round 1 simplified via x0_pre = 0.
__device__ __forceinline__ uint32_t tf_fold(uint32_t x1_init) {
  const uint32_t ks2 = 0x1BD11BDBu;
  uint32_t x0 = x1_init;                 // round 1: x0 += x1 with x0_pre = 0
  uint32_t x1 = rotl(x0, 13) ^ x0;       // round 1 rotate+xor
  x0 += x1; x1 = rotl(x1, 15) ^ x0;      // round 2
  x0 += x1; x1 = rotl(x1, 26) ^ x0;      // round 3
  x0 += x1; x1 = rotl(x1,  6) ^ x0;      // round 4
  x1 += ks2 + 1u;                        // inject ks1+ks2? no: (x0+=1 folded below, x1+=ks2+1)
  x0 += x1 + 1u;  x1 = rotl(x1, 17) ^ x0; // round 5 (v_add3 folds x0-injection)
  x0 += x1;       x1 = rotl(x1, 29) ^ x0; // round 6
  x0 += x1;       x1 = rotl(x1, 16) ^ x0; // round 7
  x0 += x1;       x1 = rotl(x1, 24) ^ x0; // round 8
  x1 += 2u;                               // inject (x0+=ks2 folded, x1+=ks0+2)
  x0 += x1 + ks2; x1 = rotl(x1, 13) ^ x0; // round 9
  x0 += x1;       x1 = rotl(x1, 15) ^ x0; // round 10
  x0 += x1;       x1 = rotl(x1, 26) ^ x0; // round 11
  x0 += x1;       x1 = rotl(x1,  6) ^ x0; // round 12
  x1 += 4u;                               // inject (x0+=ks0=0, x1+=ks1+3)
  x0 += x1;       x1 = rotl(x1, 17) ^ x0; // round 13
  x0 += x1;       x1 = rotl(x1, 29) ^ x0; // round 14
  x0 += x1;       x1 = rotl(x1, 16) ^ x0; // round 15
  x0 += x1;       x1 = rotl(x1, 24) ^ x0; // round 16
  x1 += ks2 + 4u;                         // inject (x0+=1 folded, x1+=ks2+4)
  x0 += x1 + 1u;  x1 = rotl(x1, 13) ^ x0; // round 17
  x0 += x1;       x1 = rotl(x1, 15) ^ x0; // round 18
  x0 += x1;       x1 = rotl(x1, 26) ^ x0; // round 19
  x0 += x1;       x1 = rotl(x1,  6) ^ x0; // round 20
  return (x0 + ks2) ^ (x1 + 5u);          // final inject (ks2, ks0+5) + fold
}

// Exact replica of the reference float32 pipeline for one candidate.
__device__ __forceinline__ float qval(float p, uint32_t k) {
  const float u = (float)k * 0x1p-23f;          // == jax uniform value, exact
  const float g = 1e-10f - logf(u + 1e-10f);    // gumbel_norm (g > 0 always)
  return p / g;                                  // IEEE f32 divide
}

__global__ __launch_bounds__(TPB) void gidd_sample_zt(
    const int* __restrict__ ids, const float* __restrict__ t,
    const float* __restrict__ pi, int* __restrict__ out) {
  const int row = blockIdx.x;       // b*1024 + s
  const int b = row >> 10;
  const int tid = threadIdx.x;

  const int id = ids[row];
  const uint32_t base = (uint32_t)row * (uint32_t)VOCAB;

  // Generic scan over v = it*256 + tid, it in [0,196). Packed key = (k<<8) | (255-it).
  uint32_t km = 0u;
  uint32_t cA = base + (uint32_t)tid + 1u;   // x1_init for element A (ks1 pre-added)
  uint32_t inv = 255u;                        // 255 - it for element A of the pair

#pragma unroll 1
  for (int ii = 0; ii < 98; ++ii) {           // 98 x 2 = 196 iterations
    const uint32_t bitsA = tf_fold(cA);
    const uint32_t bitsB = tf_fold(cA + 256u);
    const uint32_t keyA = ((bitsA >> 1) & 0xFFFFFF00u) | inv;
    const uint32_t keyB = ((bitsB >> 1) & 0xFFFFFF00u) | (inv - 1u);
    km = umax2(km, umax2(keyA, keyB));        // -> v_max3_u32
    cA += 512u;
    inv -= 2u;
  }
  // Peel it = 196: v = 50176 + tid, valid through v = 50256 (MASK included: safe).
  if (tid <= 80) {
    const uint32_t bits = tf_fold(cA);        // cA == base + 50176 + tid + 1
    km = umax2(km, ((bits >> 1) & 0xFFFFFF00u) | 59u);   // inv = 255 - 196
  }

  // Wave max + lowest-lane winner (exact (max k, min v) tie rule).
  uint32_t kw = km;
#pragma unroll
  for (int off = 32; off > 0; off >>= 1) kw = umax2(kw, __shfl_xor(kw, off));
  const uint64_t bal = __ballot(km == kw);
  const int lane0 = __ffsll((unsigned long long)bal) - 1;
  const int wid = tid >> 6;
  const int vw = (int)(255u - (kw & 0xFFu)) * 256 + (wid << 6) + lane0;

  __shared__ uint32_t skm[4];
  __shared__ int svm[4];
  if ((tid & 63) == 0) { skm[wid] = kw; svm[wid] = vw; }
  __syncthreads();

  if (tid == 0) {
    uint32_t kb = skm[0]; int vb = svm[0];
    for (int w = 1; w < 4; ++w)
      if (skm[w] > kb || (skm[w] == kb && svm[w] < vb)) { kb = skm[w]; vb = svm[w]; }
    const uint32_t kwin = kb >> 8;            // 23-bit mantissa of the generic winner

    const float tb = t[b];
    const float pic = pi[0];        // generic pi value (identical bits for all non-mask v)
    const float pim = pi[MASK];
    const float a = 1.0f - tb;      // alpha_t
    const float pc = tb * pic;      // generic prob
    const float pm = tb * pim;      // mask prob (without onehot)

    const uint32_t kmsk = tf_fold(base + (uint32_t)MASK + 1u) >> 9;
    const uint32_t kid  = tf_fold(base + (uint32_t)id + 1u) >> 9;

    float bq = qval(pc, kwin);
    int bv = vb;
    // MASK candidate: p strictly > pc, so ties with the (possibly spurious) generic
    // winner are impossible; index 50256 >= any label, so '>' is the right rule.
    const float pmask = (id == MASK) ? (pm + a) : pm;
    const float qm = qval(pmask, kmsk);
    if (qm > bq) { bq = qm; bv = MASK; }
    // input-id candidate (first-index-of-max rule).
    if (id != MASK) {
      const float qi = qval(pc + a, kid);
      if (qi > bq || (qi == bq && id < bv)) { bq = qi; bv = id; }
    }
    out[row] = bv;
  }
}

}  // namespace

extern "C" void kernel_launch(void* const* d_in, const int* in_sizes, int n_in,
                              void* d_out, int out_size, void* d_ws, size_t ws_size,
                              hipStream_t stream) {
  const int* ids  = (const int*)d_in[0];
  const float* t  = (const float*)d_in[1];
  const float* pi = (const float*)d_in[2];
  int* out = (int*)d_out;
  gidd_sample_zt<<<NROWS, TPB, 0, stream>>>(ids, t, pi, out);
}

// Round 4
// 415.671 us; speedup vs baseline: 1.3252x; 1.0264x over previous
//
#include <hip/hip_runtime.h>
#include <stdint.h>

// GiddLinearNoise.sample_zt on MI355X (gfx950).
//
// z_t[b,s] = argmax_v ( ((1-t_b)*onehot(id)[v] + t_b*pi[v]) / (1e-10 - log(u[b,s,v] + 1e-10)) )
// u = jax.random.uniform(key(1), (4,1024,50257), f32), partitionable threefry stream:
// bits[i] = fold(threefry2x32(key=(0,1), counter=(0,i))) = y0 ^ y1;  u = (bits>>9) * 2^-23.
//
// All generic tokens share ONE probability float => q is strictly monotone in the 23-bit
// mantissa k, so the generic argmax is (max k, min v on tie), log-free. id/MASK positions
// are included in the scan; their exact candidates (strictly larger p, same u) dominate any
// spurious win, so the 3-candidate exact epilogue is correct (see round-2 derivation).
//
// This round: inline-asm threefry core pins the static count at 66 VALU
// (v_alignbit_b32 rotates, v_add3_u32-folded x0 key-injections, literal-add x1 injections),
// + 1 v_and_or_b32 select (mask in VGPR, uniform pos tiebreak in SGPR -> 1-SGPR rule ok)
// + 0.5 v_max3_u32 + 1 counter add  =>  ~68.5 VALU/element, the practical floor.
// Packed key = (k<<9) | pos, pos = ((127-pair)<<1)|isA  (order == (k desc, v asc)).

namespace {

constexpr int VOCAB = 50257;
constexpr int MASK  = 50256;   // last index
constexpr int TPB   = 256;
constexpr int NROWS = 4096;    // B*S

// Threefry-2x32-20, key (0,1), counter (0, c). h = c + 1 (ks1 pre-folded by caller's
// counter bookkeeping). Returns y0 ^ y1. Key schedule: ks0=0, ks1=1, ks2=0x1BD11BDB;
// injections after r4:(1, ks2+1) r8:(ks2, 2) r12:(0, 4) r16:(1, ks2+4) r20:(ks2, 5).
// x0-side injections are folded into the next round's add via v_add3_u32.
// rotl(x,r) == v_alignbit_b32 x, x, 32-r.
__device__ __forceinline__ uint32_t tf_fold(uint32_t h, uint32_t ks2) {
  uint32_t x0, x1;
  asm(// r1 (x0 == h, the round-1 add with x0_pre=0 is free)
      "v_alignbit_b32 %1, %2, %2, 19\n\t"
      "v_xor_b32 %1, %1, %2\n\t"
      // r2
      "v_add_u32 %0, %2, %1\n\t"
      "v_alignbit_b32 %1, %1, %1, 17\n\t"
      "v_xor_b32 %1, %1, %0\n\t"
      // r3
      "v_add_u32 %0, %0, %1\n\t"
      "v_alignbit_b32 %1, %1, %1, 6\n\t"
      "v_xor_b32 %1, %1, %0\n\t"
      // r4
      "v_add_u32 %0, %0, %1\n\t"
      "v_alignbit_b32 %1, %1, %1, 26\n\t"
      "v_xor_b32 %1, %1, %0\n\t"
      // inject: x1 += ks2+1
      "v_add_u32 %1, 0x1BD11BDC, %1\n\t"
      // r5 (x0 += x1 + 1)
      "v_add3_u32 %0, %0, %1, 1\n\t"
      "v_alignbit_b32 %1, %1, %1, 15\n\t"
      "v_xor_b32 %1, %1, %0\n\t"
      // r6
      "v_add_u32 %0, %0, %1\n\t"
      "v_alignbit_b32 %1, %1, %1, 3\n\t"
      "v_xor_b32 %1, %1, %0\n\t"
      // r7
      "v_add_u32 %0, %0, %1\n\t"
      "v_alignbit_b32 %1, %1, %1, 16\n\t"
      "v_xor_b32 %1, %1, %0\n\t"
      // r8
      "v_add_u32 %0, %0, %1\n\t"
      "v_alignbit_b32 %1, %1, %1, 8\n\t"
      "v_xor_b32 %1, %1, %0\n\t"
      // inject: x1 += 2
      "v_add_u32 %1, 2, %1\n\t"
      // r9 (x0 += x1 + ks2)
      "v_add3_u32 %0, %0, %1, %3\n\t"
      "v_alignbit_b32 %1, %1, %1, 19\n\t"
      "v_xor_b32 %1, %1, %0\n\t"
      // r10
      "v_add_u32 %0, %0, %1\n\t"
      "v_alignbit_b32 %1, %1, %1, 17\n\t"
      "v_xor_b32 %1, %1, %0\n\t"
      // r11
      "v_add_u32 %0, %0, %1\n\t"
      "v_alignbit_b32 %1, %1, %1, 6\n\t"
      "v_xor_b32 %1, %1, %0\n\t"
      // r12
      "v_add_u32 %0, %0, %1\n\t"
      "v_alignbit_b32 %1, %1, %1, 26\n\t"
      "v_xor_b32 %1, %1, %0\n\t"
      // inject: x1 += 4
      "v_add_u32 %1, 4, %1\n\t"
      // r13
      "v_add_u32 %0, %0, %1\n\t"
      "v_alignbit_b32 %1, %1, %1, 15\n\t"
      "v_xor_b32 %1, %1, %0\n\t"
      // r14
      "v_add_u32 %0, %0, %1\n\t"
      "v_alignbit_b32 %1, %1, %1, 3\n\t"
      "v_xor_b32 %1, %1, %0\n\t"
      // r15
      "v_add_u32 %0, %0, %1\n\t"
      "v_alignbit_b32 %1, %1, %1, 16\n\t"
      "v_xor_b32 %1, %1, %0\n\t"
      // r16
      "v_add_u32 %0, %0, %1\n\t"
      "v_alignbit_b32 %1, %1, %1, 8\n\t"
      "v_xor_b32 %1, %1, %0\n\t"
      // inject: x1 += ks2+4
      "v_add_u32 %1, 0x1BD11BDF, %1\n\t"
      // r17 (x0 += x1 + 1)
      "v_add3_u32 %0, %0, %1, 1\n\t"
      "v_alignbit_b32 %1, %1, %1, 19\n\t"
      "v_xor_b32 %1, %1, %0\n\t"
      // r18
      "v_add_u32 %0, %0, %1\n\t"
      "v_alignbit_b32 %1, %1, %1, 17\n\t"
      "v_xor_b32 %1, %1, %0\n\t"
      // r19
      "v_add_u32 %0, %0, %1\n\t"
      "v_alignbit_b32 %1, %1, %1, 6\n\t"
      "v_xor_b32 %1, %1, %0\n\t"
      // r20
      "v_add_u32 %0, %0, %1\n\t"
      "v_alignbit_b32 %1, %1, %1, 26\n\t"
      "v_xor_b32 %1, %1, %0\n\t"
      // final inject (ks2, 5) + fold
      "v_add_u32 %0, %3, %0\n\t"
      "v_add_u32 %1, 5, %1\n\t"
      "v_xor_b32 %0, %0, %1"
      : "=&v"(x0), "=&v"(x1)
      : "v"(h), "s"(ks2));
  return x0;
}

// Exact replica of the reference float32 pipeline for one candidate.
__device__ __forceinline__ float qval(float p, uint32_t k) {
  const float u = (float)k * 0x1p-23f;          // == jax uniform value, exact
  const float g = 1e-10f - logf(u + 1e-10f);    // gumbel_norm (g > 0 always)
  return p / g;                                  // IEEE f32 divide
}

__global__ __launch_bounds__(TPB) void gidd_sample_zt(
    const int* __restrict__ ids, const float* __restrict__ t,
    const float* __restrict__ pi, int* __restrict__ out) {
  const int row = blockIdx.x;       // b*1024 + s
  const int b = row >> 10;
  const int tid = threadIdx.x;

  const int id = ids[row];
  const uint32_t base = (uint32_t)row * (uint32_t)VOCAB;
  const uint32_t ks2 = 0x1BD11BDBu;

  // k-field mask in a VGPR so v_and_or_b32's single SGPR slot goes to the uniform pos.
  uint32_t vmask;
  asm("v_mov_b32 %0, 0xFFFFFE00" : "=v"(vmask));

  // Generic scan over v = it*256 + tid, it in [0,197). Packed key = (k<<9) | pos,
  // pos = ((127-ii)<<1) | isA for the pair (itA=2*ii, itB=2*ii+1).
  uint32_t km = 0u;
  uint32_t hA = base + (uint32_t)tid + 1u;   // counter + ks1(=1) for element A

#pragma unroll 1
  for (uint32_t ii = 0; ii < 98u; ++ii) {
    const uint32_t hB = hA + 256u;
    const uint32_t bitsA = tf_fold(hA, ks2);
    const uint32_t bitsB = tf_fold(hB, ks2);
    const uint32_t posA = (((127u - ii) << 1) | 1u);  // uniform -> SGPR, s_alu updates
    const uint32_t posB = ((127u - ii) << 1);
    uint32_t keyA, keyB;
    asm("v_and_or_b32 %0, %1, %2, %3" : "=v"(keyA) : "v"(bitsA), "v"(vmask), "s"(posA));
    asm("v_and_or_b32 %0, %1, %2, %3" : "=v"(keyB) : "v"(bitsB), "v"(vmask), "s"(posB));
    asm("v_max3_u32 %0, %1, %2, %0" : "+v"(km) : "v"(keyA), "v"(keyB));
    hA += 512u;
  }
  // Peel it = 196 (pos = ((127-98)<<1)|1 = 59): v = 50176 + tid, valid to v = 50256.
  if (tid <= 80) {
    const uint32_t bits = tf_fold(hA, ks2);
    uint32_t key;
    asm("v_and_or_b32 %0, %1, %2, %3" : "=v"(key) : "v"(bits), "v"(vmask), "s"(59u));
    km = km > key ? km : key;
  }

  // Wave max; min-lane tie pick => exact (max k, min v).
  uint32_t kw = km;
#pragma unroll
  for (int off = 32; off > 0; off >>= 1) {
    const uint32_t o = __shfl_xor(kw, off);
    kw = kw > o ? kw : o;
  }
  const uint64_t bal = __ballot(km == kw);
  const int lane0 = __ffsll((unsigned long long)bal) - 1;
  const int wid = tid >> 6;
  const uint32_t pos = kw & 0x1FFu;
  const int it = 255 - 2 * (int)((pos >> 1) & 0x7Fu) - (int)(pos & 1u);
  const int vw = it * 256 + (wid << 6) + lane0;

  __shared__ uint32_t skm[4];
  __shared__ int svm[4];
  if ((tid & 63) == 0) { skm[wid] = kw; svm[wid] = vw; }
  __syncthreads();

  if (tid == 0) {
    uint32_t kb = skm[0]; int vb = svm[0];
    for (int w = 1; w < 4; ++w)
      if (skm[w] > kb || (skm[w] == kb && svm[w] < vb)) { kb = skm[w]; vb = svm[w]; }
    const uint32_t kwin = kb >> 9;            // 23-bit mantissa of the generic winner

    const float tb = t[b];
    const float pic = pi[0];        // generic pi value (identical bits for all non-mask v)
    const float pim = pi[MASK];
    const float a = 1.0f - tb;      // alpha_t
    const float pc = tb * pic;      // generic prob
    const float pm = tb * pim;      // mask prob (without onehot)

    const uint32_t kmsk = tf_fold(base + (uint32_t)MASK + 1u, ks2) >> 9;
    const uint32_t kid  = tf_fold(base + (uint32_t)id + 1u, ks2) >> 9;

    float bq = qval(pc, kwin);
    int bv = vb;
    // MASK candidate: p strictly > pc => never ties the generic winner; index is max.
    const float pmask = (id == MASK) ? (pm + a) : pm;
    const float qm = qval(pmask, kmsk);
    if (qm > bq) { bq = qm; bv = MASK; }
    // input-id candidate (first-index-of-max rule).
    if (id != MASK) {
      const float qi = qval(pc + a, kid);
      if (qi > bq || (qi == bq && id < bv)) { bq = qi; bv = id; }
    }
    out[row] = bv;
  }
}

}  // namespace

extern "C" void kernel_launch(void* const* d_in, const int* in_sizes, int n_in,
                              void* d_out, int out_size, void* d_ws, size_t ws_size,
                              hipStream_t stream) {
  const int* ids  = (const int*)d_in[0];
  const float* t  = (const float*)d_in[1];
  const float* pi = (const float*)d_in[2];
  int* out = (int*)d_out;
  gidd_sample_zt<<<NROWS, TPB, 0, stream>>>(ids, t, pi, out);
}